// Round 1
// baseline (1149.722 us; speedup 1.0000x reference)
//
#include <hip/hip_runtime.h>
#include <hip/hip_bf16.h>
#include <math.h>
#include <stdint.h>

// ---------------------------------------------------------------------------
// VectorTokenizer: x ->(enc MLP)-> z -> categorical(threefry key(1)) tokens
//   -> z_q = sum of codebook rows -> (dec MLP) -> rec
// Outputs concatenated: z (4096*16384) | z_q (4096*256) | rec (4096*512), f32
// ---------------------------------------------------------------------------

#define BATCH 4096
#define KTOK  32
#define VOCAB 512
#define DMODEL 512
#define ZDIM  16384   // KTOK*VOCAB
#define EDIM  256     // codebook embed dim

// ----------------------- threefry2x32 (JAX-compatible) ---------------------
__device__ __forceinline__ uint32_t rotl32(uint32_t v, int r) {
    return (v << r) | (v >> (32 - r));
}

__device__ __forceinline__ void threefry2x32(uint32_t k0, uint32_t k1,
                                             uint32_t x0, uint32_t x1,
                                             uint32_t& y0, uint32_t& y1) {
    uint32_t ks0 = k0, ks1 = k1, ks2 = k0 ^ k1 ^ 0x1BD11BDAu;
    x0 += ks0; x1 += ks1;
#define TFR(r) { x0 += x1; x1 = rotl32(x1, r); x1 ^= x0; }
    TFR(13) TFR(15) TFR(26) TFR(6)
    x0 += ks1; x1 += ks2 + 1u;
    TFR(17) TFR(29) TFR(16) TFR(24)
    x0 += ks2; x1 += ks0 + 2u;
    TFR(13) TFR(15) TFR(26) TFR(6)
    x0 += ks0; x1 += ks1 + 3u;
    TFR(17) TFR(29) TFR(16) TFR(24)
    x0 += ks1; x1 += ks2 + 4u;
    TFR(13) TFR(15) TFR(26) TFR(6)
    x0 += ks2; x1 += ks0 + 5u;
#undef TFR
    y0 = x0; y1 = x1;
}

// JAX partitionable threefry random bits, 32-bit: counter = flat index (u64),
// bits = xor-fold of the two output words.
__device__ __forceinline__ uint32_t jax_random_bits32(uint64_t e) {
    uint32_t y0, y1;
    threefry2x32(0u, 1u, (uint32_t)(e >> 32), (uint32_t)(e & 0xffffffffull), y0, y1);
    return y0 ^ y1;
}

__device__ __forceinline__ float jax_gumbel(uint64_t e) {
    const float TINY = 1.17549435e-38f;
    uint32_t bits = jax_random_bits32(e);
    float u = __uint_as_float(0x3f800000u | (bits >> 9)) - 1.0f;  // [0,1)
    u = u * 1.0f + TINY;          // matches uniform(minval=tiny, maxval=1)
    u = fmaxf(TINY, u);
    return -logf(-logf(u));
}

// ----------------------------- tiled f32 GEMM ------------------------------
// C[M,N] = act(A[M,K] @ B[K,N] + bias[N]); 128x128 tile, 256 thr, 8x8/thread
template<bool RELU>
__global__ __launch_bounds__(256)
void gemm_f32(const float* __restrict__ A, const float* __restrict__ B,
              const float* __restrict__ bias, float* __restrict__ C,
              int M, int N, int K) {
    constexpr int BM = 128, BN = 128, BK = 16, TM = 8, TN = 8;
    __shared__ __align__(16) float As[BK][BM + 4];  // A tile, transposed
    __shared__ __align__(16) float Bs[BK][BN + 4];

    const int tid = threadIdx.x;
    const int tx = tid % (BN / TN);   // 0..15
    const int ty = tid / (BN / TN);   // 0..15
    const int brow = blockIdx.y * BM;
    const int bcol = blockIdx.x * BN;

    float acc[TM][TN];
#pragma unroll
    for (int i = 0; i < TM; ++i)
#pragma unroll
        for (int j = 0; j < TN; ++j) acc[i][j] = 0.0f;

    for (int k0 = 0; k0 < K; k0 += BK) {
        // load A tile (BM x BK), store transposed
#pragma unroll
        for (int f = tid; f < BM * BK / 4; f += 256) {
            int r = f / (BK / 4);
            int c4 = f % (BK / 4);
            float4 v = *(const float4*)&A[(size_t)(brow + r) * K + k0 + c4 * 4];
            As[c4 * 4 + 0][r] = v.x;
            As[c4 * 4 + 1][r] = v.y;
            As[c4 * 4 + 2][r] = v.z;
            As[c4 * 4 + 3][r] = v.w;
        }
        // load B tile (BK x BN)
#pragma unroll
        for (int f = tid; f < BK * BN / 4; f += 256) {
            int r = f / (BN / 4);
            int c4 = f % (BN / 4);
            *(float4*)&Bs[r][c4 * 4] = *(const float4*)&B[(size_t)(k0 + r) * N + bcol + c4 * 4];
        }
        __syncthreads();

#pragma unroll
        for (int kk = 0; kk < BK; ++kk) {
            float a[TM], b[TN];
            *(float4*)&a[0] = *(const float4*)&As[kk][ty * TM];
            *(float4*)&a[4] = *(const float4*)&As[kk][ty * TM + 4];
            *(float4*)&b[0] = *(const float4*)&Bs[kk][tx * TN];
            *(float4*)&b[4] = *(const float4*)&Bs[kk][tx * TN + 4];
#pragma unroll
            for (int i = 0; i < TM; ++i)
#pragma unroll
                for (int j = 0; j < TN; ++j)
                    acc[i][j] = fmaf(a[i], b[j], acc[i][j]);
        }
        __syncthreads();
    }

    // epilogue: bias + optional relu, float4 stores
#pragma unroll
    for (int i = 0; i < TM; ++i) {
        int row = brow + ty * TM + i;
#pragma unroll
        for (int j = 0; j < TN; j += 4) {
            int col = bcol + tx * TN + j;
            float4 v;
            v.x = acc[i][j + 0] + bias[col + 0];
            v.y = acc[i][j + 1] + bias[col + 1];
            v.z = acc[i][j + 2] + bias[col + 2];
            v.w = acc[i][j + 3] + bias[col + 3];
            if (RELU) {
                v.x = fmaxf(v.x, 0.0f); v.y = fmaxf(v.y, 0.0f);
                v.z = fmaxf(v.z, 0.0f); v.w = fmaxf(v.w, 0.0f);
            }
            *(float4*)&C[(size_t)row * N + col] = v;
        }
    }
}

// -------------------- categorical sampling (1 wave / token) ----------------
__global__ __launch_bounds__(256)
void sample_tokens(const float* __restrict__ z, int* __restrict__ tokens) {
    const int wave = threadIdx.x >> 6;
    const int lane = threadIdx.x & 63;
    const size_t t = (size_t)blockIdx.x * 4 + wave;  // token index [0, 131072)
    const float* zr = z + t * VOCAB;

    // lane handles vocab entries lane*8 .. lane*8+7
    float zv[8];
    *(float4*)&zv[0] = *(const float4*)&zr[lane * 8];
    *(float4*)&zv[4] = *(const float4*)&zr[lane * 8 + 4];

    const uint64_t ebase = t * (uint64_t)VOCAB + (uint64_t)lane * 8;
    float best = -INFINITY;
    int bestv = 0;
#pragma unroll
    for (int j = 0; j < 8; ++j) {
        float g = jax_gumbel(ebase + j);
        float s = zv[j] + g;
        int v = lane * 8 + j;
        if (s > best || (s == best && v < bestv)) { best = s; bestv = v; }
    }
    // wave-wide argmax, lower index wins ties (matches jnp.argmax)
#pragma unroll
    for (int off = 32; off > 0; off >>= 1) {
        float ob = __shfl_down(best, off);
        int ov = __shfl_down(bestv, off);
        if (ob > best || (ob == best && ov < bestv)) { best = ob; bestv = ov; }
    }
    if (lane == 0) tokens[t] = bestv;
}

// ------------------------- z_q gather (1 block / row) ----------------------
__global__ __launch_bounds__(256)
void gather_zq(const int* __restrict__ tokens, const float* __restrict__ codebook,
               float* __restrict__ zq) {
    const int b = blockIdx.x;
    const int d = threadIdx.x;  // 0..255
    float s = 0.0f;
#pragma unroll
    for (int k = 0; k < KTOK; ++k) {
        int tok = tokens[b * KTOK + k];
        s += codebook[(size_t)(k * VOCAB + tok) * EDIM + d];
    }
    zq[(size_t)b * EDIM + d] = s;
}

// ------------------------------- launcher ----------------------------------
extern "C" void kernel_launch(void* const* d_in, const int* in_sizes, int n_in,
                              void* d_out, int out_size, void* d_ws, size_t ws_size,
                              hipStream_t stream) {
    const float* x   = (const float*)d_in[0];
    const float* ew1 = (const float*)d_in[1];
    const float* eb1 = (const float*)d_in[2];
    const float* ew2 = (const float*)d_in[3];
    const float* eb2 = (const float*)d_in[4];
    const float* cb  = (const float*)d_in[5];
    const float* dw1 = (const float*)d_in[6];
    const float* db1 = (const float*)d_in[7];
    const float* dw2 = (const float*)d_in[8];
    const float* db2 = (const float*)d_in[9];

    float* out = (float*)d_out;
    float* z   = out;                                   // 4096*16384
    float* zq  = out + (size_t)BATCH * ZDIM;            // 4096*256
    float* rec = zq + (size_t)BATCH * EDIM;             // 4096*512

    float* h   = (float*)d_ws;                          // 4096*512
    float* h2  = h + (size_t)BATCH * DMODEL;            // 4096*512
    int*   tok = (int*)(h2 + (size_t)BATCH * DMODEL);   // 4096*32

    dim3 blk(256);

    // encoder
    gemm_f32<true ><<<dim3(DMODEL / 128, BATCH / 128), blk, 0, stream>>>(
        x, ew1, eb1, h, BATCH, DMODEL, DMODEL);
    gemm_f32<false><<<dim3(ZDIM / 128, BATCH / 128), blk, 0, stream>>>(
        h, ew2, eb2, z, BATCH, ZDIM, DMODEL);

    // categorical sampling (JAX threefry, key(1))
    sample_tokens<<<dim3(BATCH * KTOK / 4), blk, 0, stream>>>(z, tok);

    // z_q = sum of selected codebook rows
    gather_zq<<<dim3(BATCH), blk, 0, stream>>>(tok, cb, zq);

    // decoder
    gemm_f32<true ><<<dim3(DMODEL / 128, BATCH / 128), blk, 0, stream>>>(
        zq, dw1, db1, h2, BATCH, DMODEL, EDIM);
    gemm_f32<false><<<dim3(DMODEL / 128, BATCH / 128), blk, 0, stream>>>(
        h2, dw2, db2, rec, BATCH, DMODEL, DMODEL);
}

// Round 2
// 716.555 us; speedup vs baseline: 1.6045x; 1.6045x over previous
//
#include <hip/hip_runtime.h>
#include <hip/hip_bf16.h>
#include <math.h>
#include <stdint.h>

// ---------------------------------------------------------------------------
// VectorTokenizer: x ->(enc MLP)-> z -> categorical(threefry key(1)) tokens
//   -> z_q = sum of codebook rows -> (dec MLP) -> rec
// Outputs concatenated: z (4096*16384) | z_q (4096*256) | rec (4096*512), f32
//
// Strategy (R2): big GEMM in bf16 MFMA (z threshold 1.76e-2 >> bf16 err ~7e-3);
// tokens must stay bit-exact -> two-stage sampling: bf16 argmax with top-2 gap,
// ambiguous tokens (gap < MARGIN) get exact f32 recompute of in-margin
// candidates only (same fmaf k-order that matched np in round 1).
// ---------------------------------------------------------------------------

#define BATCH 4096
#define KTOK  32
#define VOCAB 512
#define DMODEL 512
#define ZDIM  16384   // KTOK*VOCAB
#define EDIM  256     // codebook embed dim
#define MARGIN 0.03125f

typedef __attribute__((ext_vector_type(8))) short short8v;
typedef __attribute__((ext_vector_type(4))) float f32x4;

// ----------------------- threefry2x32 (JAX-compatible) ---------------------
__device__ __forceinline__ uint32_t rotl32(uint32_t v, int r) {
    return (v << r) | (v >> (32 - r));
}

__device__ __forceinline__ void threefry2x32(uint32_t k0, uint32_t k1,
                                             uint32_t x0, uint32_t x1,
                                             uint32_t& y0, uint32_t& y1) {
    uint32_t ks0 = k0, ks1 = k1, ks2 = k0 ^ k1 ^ 0x1BD11BDAu;
    x0 += ks0; x1 += ks1;
#define TFR(r) { x0 += x1; x1 = rotl32(x1, r); x1 ^= x0; }
    TFR(13) TFR(15) TFR(26) TFR(6)
    x0 += ks1; x1 += ks2 + 1u;
    TFR(17) TFR(29) TFR(16) TFR(24)
    x0 += ks2; x1 += ks0 + 2u;
    TFR(13) TFR(15) TFR(26) TFR(6)
    x0 += ks0; x1 += ks1 + 3u;
    TFR(17) TFR(29) TFR(16) TFR(24)
    x0 += ks1; x1 += ks2 + 4u;
    TFR(13) TFR(15) TFR(26) TFR(6)
    x0 += ks2; x1 += ks0 + 5u;
#undef TFR
    y0 = x0; y1 = x1;
}

__device__ __forceinline__ uint32_t jax_random_bits32(uint64_t e) {
    uint32_t y0, y1;
    threefry2x32(0u, 1u, (uint32_t)(e >> 32), (uint32_t)(e & 0xffffffffull), y0, y1);
    return y0 ^ y1;
}

__device__ __forceinline__ float jax_gumbel(uint64_t e) {
    const float TINY = 1.17549435e-38f;
    uint32_t bits = jax_random_bits32(e);
    float u = __uint_as_float(0x3f800000u | (bits >> 9)) - 1.0f;  // [0,1)
    u = u * 1.0f + TINY;
    u = fmaxf(TINY, u);
    return -logf(-logf(u));
}

__device__ __forceinline__ unsigned short f32_to_bf16_rne(float f) {
    uint32_t u = __float_as_uint(f);
    uint32_t r = (u + 0x7fffu + ((u >> 16) & 1u)) >> 16;
    return (unsigned short)r;
}

// ----------------------------- tiled f32 GEMM ------------------------------
// C[M,N] = act(A[M,K] @ B[K,N] + bias[N]); 128x128 tile, 256 thr, 8x8/thread
template<bool RELU>
__global__ __launch_bounds__(256)
void gemm_f32(const float* __restrict__ A, const float* __restrict__ B,
              const float* __restrict__ bias, float* __restrict__ C,
              int M, int N, int K) {
    constexpr int BM = 128, BN = 128, BK = 16, TM = 8, TN = 8;
    __shared__ __align__(16) float As[BK][BM + 4];
    __shared__ __align__(16) float Bs[BK][BN + 4];

    const int tid = threadIdx.x;
    const int tx = tid % (BN / TN);
    const int ty = tid / (BN / TN);
    const int brow = blockIdx.y * BM;
    const int bcol = blockIdx.x * BN;

    float acc[TM][TN];
#pragma unroll
    for (int i = 0; i < TM; ++i)
#pragma unroll
        for (int j = 0; j < TN; ++j) acc[i][j] = 0.0f;

    for (int k0 = 0; k0 < K; k0 += BK) {
#pragma unroll
        for (int f = tid; f < BM * BK / 4; f += 256) {
            int r = f / (BK / 4);
            int c4 = f % (BK / 4);
            float4 v = *(const float4*)&A[(size_t)(brow + r) * K + k0 + c4 * 4];
            As[c4 * 4 + 0][r] = v.x;
            As[c4 * 4 + 1][r] = v.y;
            As[c4 * 4 + 2][r] = v.z;
            As[c4 * 4 + 3][r] = v.w;
        }
#pragma unroll
        for (int f = tid; f < BK * BN / 4; f += 256) {
            int r = f / (BN / 4);
            int c4 = f % (BN / 4);
            *(float4*)&Bs[r][c4 * 4] = *(const float4*)&B[(size_t)(k0 + r) * N + bcol + c4 * 4];
        }
        __syncthreads();

#pragma unroll
        for (int kk = 0; kk < BK; ++kk) {
            float a[TM], b[TN];
            *(float4*)&a[0] = *(const float4*)&As[kk][ty * TM];
            *(float4*)&a[4] = *(const float4*)&As[kk][ty * TM + 4];
            *(float4*)&b[0] = *(const float4*)&Bs[kk][tx * TN];
            *(float4*)&b[4] = *(const float4*)&Bs[kk][tx * TN + 4];
#pragma unroll
            for (int i = 0; i < TM; ++i)
#pragma unroll
                for (int j = 0; j < TN; ++j)
                    acc[i][j] = fmaf(a[i], b[j], acc[i][j]);
        }
        __syncthreads();
    }

#pragma unroll
    for (int i = 0; i < TM; ++i) {
        int row = brow + ty * TM + i;
#pragma unroll
        for (int j = 0; j < TN; j += 4) {
            int col = bcol + tx * TN + j;
            float4 v;
            v.x = acc[i][j + 0] + bias[col + 0];
            v.y = acc[i][j + 1] + bias[col + 1];
            v.z = acc[i][j + 2] + bias[col + 2];
            v.w = acc[i][j + 3] + bias[col + 3];
            if (RELU) {
                v.x = fmaxf(v.x, 0.0f); v.y = fmaxf(v.y, 0.0f);
                v.z = fmaxf(v.z, 0.0f); v.w = fmaxf(v.w, 0.0f);
            }
            *(float4*)&C[(size_t)row * N + col] = v;
        }
    }
}

// --------------------- f32 -> bf16 elementwise convert ---------------------
__global__ __launch_bounds__(256)
void cvt_to_bf16(const float* __restrict__ src, unsigned short* __restrict__ dst,
                 int n) {
    int i = blockIdx.x * 256 + threadIdx.x;
    if (i * 4 < n) {
        float4 v = *(const float4*)&src[i * 4];
        ushort4 o;
        o.x = f32_to_bf16_rne(v.x);
        o.y = f32_to_bf16_rne(v.y);
        o.z = f32_to_bf16_rne(v.z);
        o.w = f32_to_bf16_rne(v.w);
        *(ushort4*)&dst[i * 4] = o;
    }
}

// ------------- f32 [R][C] -> bf16 [C][R] tiled transpose -------------------
__global__ __launch_bounds__(256)
void transpose_to_bf16(const float* __restrict__ src, unsigned short* __restrict__ dst,
                       int R, int C) {
    __shared__ float tile[32][33];
    const int c0 = blockIdx.x * 32, r0 = blockIdx.y * 32;
    const int tx = threadIdx.x % 32, ty = threadIdx.x / 32;  // 32 x 8
#pragma unroll
    for (int i = ty; i < 32; i += 8)
        tile[i][tx] = src[(size_t)(r0 + i) * C + c0 + tx];
    __syncthreads();
#pragma unroll
    for (int i = ty; i < 32; i += 8)
        dst[(size_t)(c0 + i) * R + r0 + tx] = f32_to_bf16_rne(tile[tx][i]);
}

// ------------------------- bf16 MFMA GEMM (m97-ish) ------------------------
// C[M][N] f32 = A[M][K]bf16 @ Bt[N][K]bf16^T + bias; 128x128 tile, BK=32,
// 4 waves (2x2), each wave 64x64 via 4x4 frags of mfma_f32_16x16x32_bf16.
__global__ __launch_bounds__(256)
void gemm_mfma_bf16(const unsigned short* __restrict__ A,
                    const unsigned short* __restrict__ Bt,
                    const float* __restrict__ bias,
                    float* __restrict__ C,
                    int M, int N, int K) {
    constexpr int BM = 128, BN = 128, BK = 32;
    __shared__ unsigned short As[BM * BK];  // row-major [128][32]
    __shared__ unsigned short Bs[BN * BK];  // row-major [128][32] (rows = cols of B)

    const int tid = threadIdx.x;
    const int wid = tid >> 6;
    const int lane = tid & 63;
    const int wr = wid >> 1, wc = wid & 1;
    const int l15 = lane & 15, lq = lane >> 4;
    const int brow = blockIdx.y * BM;
    const int bcol = blockIdx.x * BN;

    // staging: granule g (16B = 8 bf16) covers row g>>2, kchunk g&3
    const int g1 = tid;            // granules 0..255   (rows 0..63)
    const int g2 = tid + 256;      // granules 256..511 (rows 64..127)
    const size_t a1 = (size_t)(brow + (g1 >> 2)) * K + (g1 & 3) * 8;
    const size_t a2 = (size_t)(brow + (g2 >> 2)) * K + (g2 & 3) * 8;
    const size_t b1 = (size_t)(bcol + (g1 >> 2)) * K + (g1 & 3) * 8;
    const size_t b2 = (size_t)(bcol + (g2 >> 2)) * K + (g2 & 3) * 8;
    unsigned short* as_base1 = As + (size_t)wid * 64 * 8;          // wave-uniform
    unsigned short* as_base2 = As + (size_t)(256 + wid * 64) * 8;
    unsigned short* bs_base1 = Bs + (size_t)wid * 64 * 8;
    unsigned short* bs_base2 = Bs + (size_t)(256 + wid * 64) * 8;

    f32x4 acc[4][4];
#pragma unroll
    for (int m = 0; m < 4; ++m)
#pragma unroll
        for (int n = 0; n < 4; ++n) acc[m][n] = (f32x4){0.f, 0.f, 0.f, 0.f};

    for (int k0 = 0; k0 < K; k0 += BK) {
        __builtin_amdgcn_global_load_lds(
            (const __attribute__((address_space(1))) unsigned int*)(A + a1 + k0),
            (__attribute__((address_space(3))) unsigned int*)as_base1, 16, 0, 0);
        __builtin_amdgcn_global_load_lds(
            (const __attribute__((address_space(1))) unsigned int*)(A + a2 + k0),
            (__attribute__((address_space(3))) unsigned int*)as_base2, 16, 0, 0);
        __builtin_amdgcn_global_load_lds(
            (const __attribute__((address_space(1))) unsigned int*)(Bt + b1 + k0),
            (__attribute__((address_space(3))) unsigned int*)bs_base1, 16, 0, 0);
        __builtin_amdgcn_global_load_lds(
            (const __attribute__((address_space(1))) unsigned int*)(Bt + b2 + k0),
            (__attribute__((address_space(3))) unsigned int*)bs_base2, 16, 0, 0);
        __syncthreads();

        short8v af[4], bf[4];
#pragma unroll
        for (int m = 0; m < 4; ++m)
            af[m] = *(const short8v*)&As[(wr * 64 + m * 16 + l15) * BK + lq * 8];
#pragma unroll
        for (int n = 0; n < 4; ++n)
            bf[n] = *(const short8v*)&Bs[(wc * 64 + n * 16 + l15) * BK + lq * 8];
#pragma unroll
        for (int m = 0; m < 4; ++m)
#pragma unroll
            for (int n = 0; n < 4; ++n)
                acc[m][n] = __builtin_amdgcn_mfma_f32_16x16x32_bf16(
                    af[m], bf[n], acc[m][n], 0, 0, 0);
        __syncthreads();
    }

    // epilogue: C/D layout col = lane&15, row = (lane>>4)*4 + reg
#pragma unroll
    for (int m = 0; m < 4; ++m) {
#pragma unroll
        for (int n = 0; n < 4; ++n) {
            int col = bcol + wc * 64 + n * 16 + l15;
            float bv = bias[col];
#pragma unroll
            for (int r = 0; r < 4; ++r) {
                int row = brow + wr * 64 + m * 16 + lq * 4 + r;
                C[(size_t)row * N + col] = acc[m][n][r] + bv;
            }
        }
    }
}

// ----------- categorical sampling w/ top-2 gap (1 wave / token) ------------
__global__ __launch_bounds__(256)
void sample_tokens_gap(const float* __restrict__ z, int* __restrict__ tokens,
                       float* __restrict__ s1v, int* __restrict__ amb,
                       int* __restrict__ ambCount) {
    const int wave = threadIdx.x >> 6;
    const int lane = threadIdx.x & 63;
    const size_t t = (size_t)blockIdx.x * 4 + wave;
    const float* zr = z + t * VOCAB;

    float s1 = -INFINITY, s2 = -INFINITY;
    int v1 = 0;
    // lane covers elements lane*4..+3 and 256+lane*4..+3 (coalesced float4)
#pragma unroll
    for (int half = 0; half < 2; ++half) {
        int e0 = half * 256 + lane * 4;
        float4 zv = *(const float4*)&zr[e0];
        float zs[4] = {zv.x, zv.y, zv.z, zv.w};
#pragma unroll
        for (int j = 0; j < 4; ++j) {
            int v = e0 + j;
            float s = zs[j] + jax_gumbel(t * (uint64_t)VOCAB + v);
            if (s > s1 || (s == s1 && v < v1)) { s2 = s1; s1 = s; v1 = v; }
            else if (s > s2) s2 = s;
        }
    }
#pragma unroll
    for (int off = 32; off > 0; off >>= 1) {
        float os1 = __shfl_down(s1, off);
        int ov1 = __shfl_down(v1, off);
        float os2 = __shfl_down(s2, off);
        if (os1 > s1 || (os1 == s1 && ov1 < v1)) {
            s2 = fmaxf(s1, os2); s1 = os1; v1 = ov1;
        } else {
            s2 = fmaxf(os1, s2);
        }
    }
    if (lane == 0) {
        tokens[t] = v1;
        s1v[t] = s1;
        if (s1 - s2 < MARGIN) {
            int idx = atomicAdd(ambCount, 1);
            amb[idx] = (int)t;
        }
    }
}

// --------- exact refinement of ambiguous tokens (1 wave / token) -----------
__global__ __launch_bounds__(64)
void refine_tokens(const float* __restrict__ z, const float* __restrict__ h,
                   const float* __restrict__ w2, const float* __restrict__ eb2,
                   const int* __restrict__ amb, const int* __restrict__ ambCount,
                   const float* __restrict__ s1v, int* __restrict__ tok) {
    const int cnt = *ambCount;
    const int lane = threadIdx.x;
    for (int i = blockIdx.x; i < cnt; i += gridDim.x) {
        const int t = amb[i];
        const int b = t >> 5;        // token row
        const int kb = t & 31;       // block within row
        const float* zr = z + (size_t)t * VOCAB;
        const float s1 = s1v[t];
        float bestE = -INFINITY;
        int bestV = VOCAB;
#pragma unroll 1
        for (int r = 0; r < 8; ++r) {
            const int v = r * 64 + lane;
            const float g = jax_gumbel((uint64_t)t * VOCAB + v);
            const float sbf = zr[v] + g;
            float ex = -INFINITY;
            if (sbf >= s1 - MARGIN) {
                // exact f32 recompute, k ascending, fmaf (matches np path)
                const float* hr = h + (size_t)b * DMODEL;
                const float* wcol = w2 + (size_t)(kb * VOCAB + v);
                float acc = 0.f;
#pragma unroll 8
                for (int k = 0; k < DMODEL; ++k)
                    acc = fmaf(hr[k], wcol[(size_t)k * ZDIM], acc);
                ex = acc + eb2[kb * VOCAB + v] + g;
            }
            if (ex > bestE || (ex == bestE && v < bestV)) { bestE = ex; bestV = v; }
        }
#pragma unroll
        for (int off = 32; off > 0; off >>= 1) {
            float oe = __shfl_down(bestE, off);
            int ov = __shfl_down(bestV, off);
            if (oe > bestE || (oe == bestE && ov < bestV)) { bestE = oe; bestV = ov; }
        }
        if (lane == 0) tok[t] = bestV;
    }
}

// ----------------- simple sampler (ws-too-small fallback) ------------------
__global__ __launch_bounds__(256)
void sample_tokens_simple(const float* __restrict__ z, int* __restrict__ tokens) {
    const int wave = threadIdx.x >> 6;
    const int lane = threadIdx.x & 63;
    const size_t t = (size_t)blockIdx.x * 4 + wave;
    const float* zr = z + t * VOCAB;
    float zv[8];
    *(float4*)&zv[0] = *(const float4*)&zr[lane * 8];
    *(float4*)&zv[4] = *(const float4*)&zr[lane * 8 + 4];
    const uint64_t ebase = t * (uint64_t)VOCAB + (uint64_t)lane * 8;
    float best = -INFINITY;
    int bestv = 0;
#pragma unroll
    for (int j = 0; j < 8; ++j) {
        float g = jax_gumbel(ebase + j);
        float s = zv[j] + g;
        int v = lane * 8 + j;
        if (s > best || (s == best && v < bestv)) { best = s; bestv = v; }
    }
#pragma unroll
    for (int off = 32; off > 0; off >>= 1) {
        float ob = __shfl_down(best, off);
        int ov = __shfl_down(bestv, off);
        if (ob > best || (ob == best && ov < bestv)) { best = ob; bestv = ov; }
    }
    if (lane == 0) tokens[t] = bestv;
}

__global__ __launch_bounds__(64)
void zero_count(int* p) { if (threadIdx.x == 0) *p = 0; }

// ------------------------- z_q gather (1 block / row) ----------------------
__global__ __launch_bounds__(256)
void gather_zq(const int* __restrict__ tokens, const float* __restrict__ codebook,
               float* __restrict__ zq) {
    const int b = blockIdx.x;
    const int d = threadIdx.x;
    float s = 0.0f;
#pragma unroll
    for (int k = 0; k < KTOK; ++k) {
        int tok = tokens[b * KTOK + k];
        s += codebook[(size_t)(k * VOCAB + tok) * EDIM + d];
    }
    zq[(size_t)b * EDIM + d] = s;
}

// ------------------------------- launcher ----------------------------------
extern "C" void kernel_launch(void* const* d_in, const int* in_sizes, int n_in,
                              void* d_out, int out_size, void* d_ws, size_t ws_size,
                              hipStream_t stream) {
    const float* x   = (const float*)d_in[0];
    const float* ew1 = (const float*)d_in[1];
    const float* eb1 = (const float*)d_in[2];
    const float* ew2 = (const float*)d_in[3];
    const float* eb2 = (const float*)d_in[4];
    const float* cb  = (const float*)d_in[5];
    const float* dw1 = (const float*)d_in[6];
    const float* db1 = (const float*)d_in[7];
    const float* dw2 = (const float*)d_in[8];
    const float* db2 = (const float*)d_in[9];

    float* out = (float*)d_out;
    float* z   = out;
    float* zq  = out + (size_t)BATCH * ZDIM;
    float* rec = zq + (size_t)BATCH * EDIM;

    char* ws = (char*)d_ws;
    float* h    = (float*)(ws);                         // 8 MB
    float* h2   = (float*)(ws + 8388608);               // 8 MB
    unsigned short* hb   = (unsigned short*)(ws + 16777216);  // 4 MB
    unsigned short* w2bt = (unsigned short*)(ws + 20971520);  // 16.75 MB
    int*   tok  = (int*)(ws + 37748736);                // 512 KB
    float* s1v  = (float*)(ws + 38273024);              // 512 KB
    int*   amb  = (int*)(ws + 38797312);                // 512 KB
    int*   cnt  = (int*)(ws + 39321600);
    const size_t WS_NEED = 39321856;

    dim3 blk(256);
    const bool fast = ws_size >= WS_NEED;

    // encoder layer 1 (f32 exact — feeds the exact-recompute path)
    gemm_f32<true ><<<dim3(DMODEL / 128, BATCH / 128), blk, 0, stream>>>(
        x, ew1, eb1, h, BATCH, DMODEL, DMODEL);

    if (fast) {
        // convert h -> bf16; transpose+convert w2 -> [N][K] bf16
        cvt_to_bf16<<<dim3(BATCH * DMODEL / 4 / 256), blk, 0, stream>>>(
            h, hb, BATCH * DMODEL);
        transpose_to_bf16<<<dim3(ZDIM / 32, DMODEL / 32), blk, 0, stream>>>(
            ew2, w2bt, DMODEL, ZDIM);
        // big GEMM via bf16 MFMA
        gemm_mfma_bf16<<<dim3(ZDIM / 128, BATCH / 128), blk, 0, stream>>>(
            hb, w2bt, eb2, z, BATCH, ZDIM, DMODEL);
        // two-stage sampling
        zero_count<<<dim3(1), dim3(64), 0, stream>>>(cnt);
        sample_tokens_gap<<<dim3(BATCH * KTOK / 4), blk, 0, stream>>>(
            z, tok, s1v, amb, cnt);
        refine_tokens<<<dim3(2048), dim3(64), 0, stream>>>(
            z, h, ew2, eb2, amb, cnt, s1v, tok);
    } else {
        // fallback: all-f32 path (round-1)
        gemm_f32<false><<<dim3(ZDIM / 128, BATCH / 128), blk, 0, stream>>>(
            h, ew2, eb2, z, BATCH, ZDIM, DMODEL);
        sample_tokens_simple<<<dim3(BATCH * KTOK / 4), blk, 0, stream>>>(z, tok);
    }

    // z_q = sum of selected codebook rows
    gather_zq<<<dim3(BATCH), blk, 0, stream>>>(tok, cb, zq);

    // decoder (f32 exact)
    gemm_f32<true ><<<dim3(DMODEL / 128, BATCH / 128), blk, 0, stream>>>(
        zq, dw1, db1, h2, BATCH, DMODEL, EDIM);
    gemm_f32<false><<<dim3(DMODEL / 128, BATCH / 128), blk, 0, stream>>>(
        h2, dw2, db2, rec, BATCH, DMODEL, DMODEL);
}

// Round 3
// 571.291 us; speedup vs baseline: 2.0125x; 1.2543x over previous
//
#include <hip/hip_runtime.h>
#include <hip/hip_bf16.h>
#include <math.h>
#include <stdint.h>

// ---------------------------------------------------------------------------
// VectorTokenizer: x ->(enc MLP)-> z -> categorical(threefry key(1)) tokens
//   -> z_q = sum of codebook rows -> (dec MLP) -> rec
// Outputs concatenated: z (4096*16384) | z_q (4096*256) | rec (4096*512), f32
//
// R3: sampler uses fast hw-log gumbel (filter only; exact refine unchanged),
// small f32 GEMMs 64x64-tiled (grid 512 blocks, k-ascending fmaf chain kept
// for np bit-exactness), MFMA GEMM gets XCD-aware block swizzle.
// ---------------------------------------------------------------------------

#define BATCH 4096
#define KTOK  32
#define VOCAB 512
#define DMODEL 512
#define ZDIM  16384
#define EDIM  256
#define MARGIN 0.03125f

typedef __attribute__((ext_vector_type(8))) short short8v;
typedef __attribute__((ext_vector_type(4))) float f32x4;

// ----------------------- threefry2x32 (JAX-compatible) ---------------------
__device__ __forceinline__ uint32_t rotl32(uint32_t v, int r) {
    return (v << r) | (v >> (32 - r));
}

__device__ __forceinline__ void threefry2x32(uint32_t k0, uint32_t k1,
                                             uint32_t x0, uint32_t x1,
                                             uint32_t& y0, uint32_t& y1) {
    uint32_t ks0 = k0, ks1 = k1, ks2 = k0 ^ k1 ^ 0x1BD11BDAu;
    x0 += ks0; x1 += ks1;
#define TFR(r) { x0 += x1; x1 = rotl32(x1, r); x1 ^= x0; }
    TFR(13) TFR(15) TFR(26) TFR(6)
    x0 += ks1; x1 += ks2 + 1u;
    TFR(17) TFR(29) TFR(16) TFR(24)
    x0 += ks2; x1 += ks0 + 2u;
    TFR(13) TFR(15) TFR(26) TFR(6)
    x0 += ks0; x1 += ks1 + 3u;
    TFR(17) TFR(29) TFR(16) TFR(24)
    x0 += ks1; x1 += ks2 + 4u;
    TFR(13) TFR(15) TFR(26) TFR(6)
    x0 += ks2; x1 += ks0 + 5u;
#undef TFR
    y0 = x0; y1 = x1;
}

// exact path (refine): matches JAX bit-for-bit
__device__ __forceinline__ float jax_gumbel(uint64_t e) {
    const float TINY = 1.17549435e-38f;
    uint32_t y0, y1;
    threefry2x32(0u, 1u, (uint32_t)(e >> 32), (uint32_t)(e & 0xffffffffull), y0, y1);
    uint32_t bits = y0 ^ y1;
    float u = __uint_as_float(0x3f800000u | (bits >> 9)) - 1.0f;
    u = u * 1.0f + TINY;
    u = fmaxf(TINY, u);
    return -logf(-logf(u));
}

// fast path (sampler filter): |g_fast - g_exact| <~ 1e-4 << MARGIN
__device__ __forceinline__ float fast_gumbel(uint32_t e32) {
    const float TINY = 1.17549435e-38f;
    const float LN2 = 0.69314718056f;
    uint32_t y0, y1;
    threefry2x32(0u, 1u, 0u, e32, y0, y1);   // high counter word is always 0
    uint32_t bits = y0 ^ y1;
    float f = __uint_as_float(0x3f800000u | (bits >> 9));  // [1,2)
    float u = f - 1.0f;          // exact (Sterbenz)
    float d = 2.0f - f;          // exact = 1-u, in (0,1]
    u = fmaxf(u, TINY);
    float e_hw = -LN2 * __builtin_amdgcn_logf(u);            // -ln u, hw log2
    float e_poly = d * fmaf(d, fmaf(d, 0.33333333f, 0.5f), 1.0f); // d+d^2/2+d^3/3
    float e = (d < 0.002f) ? e_poly : e_hw;
    return -LN2 * __builtin_amdgcn_logf(e);
}

__device__ __forceinline__ unsigned short f32_to_bf16_rne(float f) {
    uint32_t u = __float_as_uint(f);
    uint32_t r = (u + 0x7fffu + ((u >> 16) & 1u)) >> 16;
    return (unsigned short)r;
}

// ------------------ tiled f32 GEMM, 64x64 (small layers) -------------------
// k-ascending single fmaf chain per output => bit-exact vs np/Eigen
template<bool RELU>
__global__ __launch_bounds__(256)
void gemm_f32_64(const float* __restrict__ A, const float* __restrict__ B,
                 const float* __restrict__ bias, float* __restrict__ C,
                 int M, int N, int K) {
    constexpr int BK = 16;
    __shared__ __align__(16) float As[BK][68];
    __shared__ __align__(16) float Bs[BK][68];

    const int tid = threadIdx.x;
    const int tx = tid % 16;
    const int ty = tid / 16;
    const int brow = blockIdx.y * 64;
    const int bcol = blockIdx.x * 64;

    float acc[4][4] = {};

    for (int k0 = 0; k0 < K; k0 += BK) {
        {   // A tile 64x16, transposed store
            int r = tid >> 2, c4 = tid & 3;
            float4 v = *(const float4*)&A[(size_t)(brow + r) * K + k0 + c4 * 4];
            As[c4 * 4 + 0][r] = v.x;
            As[c4 * 4 + 1][r] = v.y;
            As[c4 * 4 + 2][r] = v.z;
            As[c4 * 4 + 3][r] = v.w;
        }
        {   // B tile 16x64
            int r = tid >> 4, c4 = tid & 15;
            *(float4*)&Bs[r][c4 * 4] = *(const float4*)&B[(size_t)(k0 + r) * N + bcol + c4 * 4];
        }
        __syncthreads();

#pragma unroll
        for (int kk = 0; kk < BK; ++kk) {
            float a[4], b[4];
            *(float4*)&a[0] = *(const float4*)&As[kk][ty * 4];
            *(float4*)&b[0] = *(const float4*)&Bs[kk][tx * 4];
#pragma unroll
            for (int i = 0; i < 4; ++i)
#pragma unroll
                for (int j = 0; j < 4; ++j)
                    acc[i][j] = fmaf(a[i], b[j], acc[i][j]);
        }
        __syncthreads();
    }

#pragma unroll
    for (int i = 0; i < 4; ++i) {
        int row = brow + ty * 4 + i;
        int col = bcol + tx * 4;
        float4 v;
        v.x = acc[i][0] + bias[col + 0];
        v.y = acc[i][1] + bias[col + 1];
        v.z = acc[i][2] + bias[col + 2];
        v.w = acc[i][3] + bias[col + 3];
        if (RELU) {
            v.x = fmaxf(v.x, 0.0f); v.y = fmaxf(v.y, 0.0f);
            v.z = fmaxf(v.z, 0.0f); v.w = fmaxf(v.w, 0.0f);
        }
        *(float4*)&C[(size_t)row * N + col] = v;
    }
}

// ---------------- tiled f32 GEMM, 128x128 (fallback big) -------------------
template<bool RELU>
__global__ __launch_bounds__(256)
void gemm_f32(const float* __restrict__ A, const float* __restrict__ B,
              const float* __restrict__ bias, float* __restrict__ C,
              int M, int N, int K) {
    constexpr int BM = 128, BN = 128, BK = 16, TM = 8, TN = 8;
    __shared__ __align__(16) float As[BK][BM + 4];
    __shared__ __align__(16) float Bs[BK][BN + 4];

    const int tid = threadIdx.x;
    const int tx = tid % (BN / TN);
    const int ty = tid / (BN / TN);
    const int brow = blockIdx.y * BM;
    const int bcol = blockIdx.x * BN;

    float acc[TM][TN] = {};

    for (int k0 = 0; k0 < K; k0 += BK) {
#pragma unroll
        for (int f = tid; f < BM * BK / 4; f += 256) {
            int r = f / (BK / 4);
            int c4 = f % (BK / 4);
            float4 v = *(const float4*)&A[(size_t)(brow + r) * K + k0 + c4 * 4];
            As[c4 * 4 + 0][r] = v.x;
            As[c4 * 4 + 1][r] = v.y;
            As[c4 * 4 + 2][r] = v.z;
            As[c4 * 4 + 3][r] = v.w;
        }
#pragma unroll
        for (int f = tid; f < BK * BN / 4; f += 256) {
            int r = f / (BN / 4);
            int c4 = f % (BN / 4);
            *(float4*)&Bs[r][c4 * 4] = *(const float4*)&B[(size_t)(k0 + r) * N + bcol + c4 * 4];
        }
        __syncthreads();

#pragma unroll
        for (int kk = 0; kk < BK; ++kk) {
            float a[TM], b[TN];
            *(float4*)&a[0] = *(const float4*)&As[kk][ty * TM];
            *(float4*)&a[4] = *(const float4*)&As[kk][ty * TM + 4];
            *(float4*)&b[0] = *(const float4*)&Bs[kk][tx * TN];
            *(float4*)&b[4] = *(const float4*)&Bs[kk][tx * TN + 4];
#pragma unroll
            for (int i = 0; i < TM; ++i)
#pragma unroll
                for (int j = 0; j < TN; ++j)
                    acc[i][j] = fmaf(a[i], b[j], acc[i][j]);
        }
        __syncthreads();
    }

#pragma unroll
    for (int i = 0; i < TM; ++i) {
        int row = brow + ty * TM + i;
#pragma unroll
        for (int j = 0; j < TN; j += 4) {
            int col = bcol + tx * TN + j;
            float4 v;
            v.x = acc[i][j + 0] + bias[col + 0];
            v.y = acc[i][j + 1] + bias[col + 1];
            v.z = acc[i][j + 2] + bias[col + 2];
            v.w = acc[i][j + 3] + bias[col + 3];
            if (RELU) {
                v.x = fmaxf(v.x, 0.0f); v.y = fmaxf(v.y, 0.0f);
                v.z = fmaxf(v.z, 0.0f); v.w = fmaxf(v.w, 0.0f);
            }
            *(float4*)&C[(size_t)row * N + col] = v;
        }
    }
}

// --------------------- f32 -> bf16 elementwise convert ---------------------
__global__ __launch_bounds__(256)
void cvt_to_bf16(const float* __restrict__ src, unsigned short* __restrict__ dst,
                 int n) {
    int i = blockIdx.x * 256 + threadIdx.x;
    if (i * 4 < n) {
        float4 v = *(const float4*)&src[i * 4];
        ushort4 o;
        o.x = f32_to_bf16_rne(v.x);
        o.y = f32_to_bf16_rne(v.y);
        o.z = f32_to_bf16_rne(v.z);
        o.w = f32_to_bf16_rne(v.w);
        *(ushort4*)&dst[i * 4] = o;
    }
}

// ------------- f32 [R][C] -> bf16 [C][R] tiled transpose -------------------
__global__ __launch_bounds__(256)
void transpose_to_bf16(const float* __restrict__ src, unsigned short* __restrict__ dst,
                       int R, int C) {
    __shared__ float tile[32][33];
    const int c0 = blockIdx.x * 32, r0 = blockIdx.y * 32;
    const int tx = threadIdx.x % 32, ty = threadIdx.x / 32;
#pragma unroll
    for (int i = ty; i < 32; i += 8)
        tile[i][tx] = src[(size_t)(r0 + i) * C + c0 + tx];
    __syncthreads();
#pragma unroll
    for (int i = ty; i < 32; i += 8)
        dst[(size_t)(c0 + i) * R + r0 + tx] = f32_to_bf16_rne(tile[tx][i]);
}

// ------------------------- bf16 MFMA GEMM ----------------------------------
// C[M][N] f32 = A[M][K]bf16 @ Bt[N][K]bf16^T + bias; 128x128 tile, BK=32,
// 4 waves (2x2), each wave 64x64 via 4x4 frags of mfma_f32_16x16x32_bf16.
// XCD-aware bijective block swizzle (grid 4096 % 8 == 0).
__global__ __launch_bounds__(256)
void gemm_mfma_bf16(const unsigned short* __restrict__ A,
                    const unsigned short* __restrict__ Bt,
                    const float* __restrict__ bias,
                    float* __restrict__ C,
                    int M, int N, int K) {
    constexpr int BM = 128, BN = 128, BK = 32;
    __shared__ unsigned short As[BM * BK];
    __shared__ unsigned short Bs[BN * BK];

    // XCD swizzle: linear id -> contiguous chunk per XCD
    const int nwg = gridDim.x * gridDim.y;
    const int lid = blockIdx.y * gridDim.x + blockIdx.x;
    const int cpx = nwg >> 3;                       // nwg % 8 == 0
    const int swz = (lid & 7) * cpx + (lid >> 3);
    const int bx = swz % gridDim.x;
    const int by = swz / gridDim.x;

    const int tid = threadIdx.x;
    const int wid = tid >> 6;
    const int lane = tid & 63;
    const int wr = wid >> 1, wc = wid & 1;
    const int l15 = lane & 15, lq = lane >> 4;
    const int brow = by * BM;
    const int bcol = bx * BN;

    const int g1 = tid;
    const int g2 = tid + 256;
    const size_t a1 = (size_t)(brow + (g1 >> 2)) * K + (g1 & 3) * 8;
    const size_t a2 = (size_t)(brow + (g2 >> 2)) * K + (g2 & 3) * 8;
    const size_t b1 = (size_t)(bcol + (g1 >> 2)) * K + (g1 & 3) * 8;
    const size_t b2 = (size_t)(bcol + (g2 >> 2)) * K + (g2 & 3) * 8;
    unsigned short* as_base1 = As + (size_t)wid * 64 * 8;
    unsigned short* as_base2 = As + (size_t)(256 + wid * 64) * 8;
    unsigned short* bs_base1 = Bs + (size_t)wid * 64 * 8;
    unsigned short* bs_base2 = Bs + (size_t)(256 + wid * 64) * 8;

    f32x4 acc[4][4];
#pragma unroll
    for (int m = 0; m < 4; ++m)
#pragma unroll
        for (int n = 0; n < 4; ++n) acc[m][n] = (f32x4){0.f, 0.f, 0.f, 0.f};

    for (int k0 = 0; k0 < K; k0 += BK) {
        __builtin_amdgcn_global_load_lds(
            (const __attribute__((address_space(1))) unsigned int*)(A + a1 + k0),
            (__attribute__((address_space(3))) unsigned int*)as_base1, 16, 0, 0);
        __builtin_amdgcn_global_load_lds(
            (const __attribute__((address_space(1))) unsigned int*)(A + a2 + k0),
            (__attribute__((address_space(3))) unsigned int*)as_base2, 16, 0, 0);
        __builtin_amdgcn_global_load_lds(
            (const __attribute__((address_space(1))) unsigned int*)(Bt + b1 + k0),
            (__attribute__((address_space(3))) unsigned int*)bs_base1, 16, 0, 0);
        __builtin_amdgcn_global_load_lds(
            (const __attribute__((address_space(1))) unsigned int*)(Bt + b2 + k0),
            (__attribute__((address_space(3))) unsigned int*)bs_base2, 16, 0, 0);
        __syncthreads();

        short8v af[4], bf[4];
#pragma unroll
        for (int m = 0; m < 4; ++m)
            af[m] = *(const short8v*)&As[(wr * 64 + m * 16 + l15) * BK + lq * 8];
#pragma unroll
        for (int n = 0; n < 4; ++n)
            bf[n] = *(const short8v*)&Bs[(wc * 64 + n * 16 + l15) * BK + lq * 8];
#pragma unroll
        for (int m = 0; m < 4; ++m)
#pragma unroll
            for (int n = 0; n < 4; ++n)
                acc[m][n] = __builtin_amdgcn_mfma_f32_16x16x32_bf16(
                    af[m], bf[n], acc[m][n], 0, 0, 0);
        __syncthreads();
    }

#pragma unroll
    for (int m = 0; m < 4; ++m) {
#pragma unroll
        for (int n = 0; n < 4; ++n) {
            int col = bcol + wc * 64 + n * 16 + l15;
            float bv = bias[col];
#pragma unroll
            for (int r = 0; r < 4; ++r) {
                int row = brow + wr * 64 + m * 16 + lq * 4 + r;
                C[(size_t)row * N + col] = acc[m][n][r] + bv;
            }
        }
    }
}

// ----------- categorical sampling w/ top-2 gap (1 wave / token) ------------
__global__ __launch_bounds__(256)
void sample_tokens_gap(const float* __restrict__ z, int* __restrict__ tokens,
                       float* __restrict__ s1v, int* __restrict__ amb,
                       int* __restrict__ ambCount) {
    const int wave = threadIdx.x >> 6;
    const int lane = threadIdx.x & 63;
    const uint32_t t = blockIdx.x * 4 + wave;
    const float* zr = z + (size_t)t * VOCAB;

    float s1 = -INFINITY, s2 = -INFINITY;
    int v1 = 0;
#pragma unroll
    for (int half = 0; half < 2; ++half) {
        int e0 = half * 256 + lane * 4;
        float4 zv = *(const float4*)&zr[e0];
        float zs[4] = {zv.x, zv.y, zv.z, zv.w};
#pragma unroll
        for (int j = 0; j < 4; ++j) {
            int v = e0 + j;
            float s = zs[j] + fast_gumbel(t * (uint32_t)VOCAB + v);
            if (s > s1 || (s == s1 && v < v1)) { s2 = s1; s1 = s; v1 = v; }
            else if (s > s2) s2 = s;
        }
    }
#pragma unroll
    for (int off = 32; off > 0; off >>= 1) {
        float os1 = __shfl_down(s1, off);
        int ov1 = __shfl_down(v1, off);
        float os2 = __shfl_down(s2, off);
        if (os1 > s1 || (os1 == s1 && ov1 < v1)) {
            s2 = fmaxf(s1, os2); s1 = os1; v1 = ov1;
        } else {
            s2 = fmaxf(os1, s2);
        }
    }
    if (lane == 0) {
        tokens[t] = v1;
        s1v[t] = s1;
        if (s1 - s2 < MARGIN) {
            int idx = atomicAdd(ambCount, 1);
            amb[idx] = (int)t;
        }
    }
}

// --------- exact refinement of ambiguous tokens (1 wave / token) -----------
__global__ __launch_bounds__(64)
void refine_tokens(const float* __restrict__ z, const float* __restrict__ h,
                   const float* __restrict__ w2, const float* __restrict__ eb2,
                   const int* __restrict__ amb, const int* __restrict__ ambCount,
                   const float* __restrict__ s1v, int* __restrict__ tok) {
    const int cnt = *ambCount;
    const int lane = threadIdx.x;
    for (int i = blockIdx.x; i < cnt; i += gridDim.x) {
        const int t = amb[i];
        const int b = t >> 5;
        const int kb = t & 31;
        const float* zr = z + (size_t)t * VOCAB;
        const float s1 = s1v[t];
        float bestE = -INFINITY;
        int bestV = VOCAB;
#pragma unroll 1
        for (int r = 0; r < 8; ++r) {
            const int v = r * 64 + lane;
            const float g = jax_gumbel((uint64_t)t * VOCAB + v);
            const float sbf = zr[v] + g;
            float ex = -INFINITY;
            if (sbf >= s1 - MARGIN) {
                const float* hr = h + (size_t)b * DMODEL;
                const float* wcol = w2 + (size_t)(kb * VOCAB + v);
                float acc = 0.f;
#pragma unroll 8
                for (int k = 0; k < DMODEL; ++k)
                    acc = fmaf(hr[k], wcol[(size_t)k * ZDIM], acc);
                ex = acc + eb2[kb * VOCAB + v] + g;
            }
            if (ex > bestE || (ex == bestE && v < bestV)) { bestE = ex; bestV = v; }
        }
#pragma unroll
        for (int off = 32; off > 0; off >>= 1) {
            float oe = __shfl_down(bestE, off);
            int ov = __shfl_down(bestV, off);
            if (oe > bestE || (oe == bestE && ov < bestV)) { bestE = oe; bestV = ov; }
        }
        if (lane == 0) tok[t] = bestV;
    }
}

// ----------------- simple sampler (ws-too-small fallback) ------------------
__global__ __launch_bounds__(256)
void sample_tokens_simple(const float* __restrict__ z, int* __restrict__ tokens) {
    const int wave = threadIdx.x >> 6;
    const int lane = threadIdx.x & 63;
    const size_t t = (size_t)blockIdx.x * 4 + wave;
    const float* zr = z + t * VOCAB;
    float zv[8];
    *(float4*)&zv[0] = *(const float4*)&zr[lane * 8];
    *(float4*)&zv[4] = *(const float4*)&zr[lane * 8 + 4];
    const uint64_t ebase = t * (uint64_t)VOCAB + (uint64_t)lane * 8;
    float best = -INFINITY;
    int bestv = 0;
#pragma unroll
    for (int j = 0; j < 8; ++j) {
        float g = jax_gumbel(ebase + j);
        float s = zv[j] + g;
        int v = lane * 8 + j;
        if (s > best || (s == best && v < bestv)) { best = s; bestv = v; }
    }
#pragma unroll
    for (int off = 32; off > 0; off >>= 1) {
        float ob = __shfl_down(best, off);
        int ov = __shfl_down(bestv, off);
        if (ob > best || (ob == best && ov < bestv)) { best = ob; bestv = ov; }
    }
    if (lane == 0) tokens[t] = bestv;
}

__global__ __launch_bounds__(64)
void zero_count(int* p) { if (threadIdx.x == 0) *p = 0; }

// ------------------------- z_q gather (1 block / row) ----------------------
__global__ __launch_bounds__(256)
void gather_zq(const int* __restrict__ tokens, const float* __restrict__ codebook,
               float* __restrict__ zq) {
    const int b = blockIdx.x;
    const int d = threadIdx.x;
    float s = 0.0f;
#pragma unroll
    for (int k = 0; k < KTOK; ++k) {
        int tok = tokens[b * KTOK + k];
        s += codebook[(size_t)(k * VOCAB + tok) * EDIM + d];
    }
    zq[(size_t)b * EDIM + d] = s;
}

// ------------------------------- launcher ----------------------------------
extern "C" void kernel_launch(void* const* d_in, const int* in_sizes, int n_in,
                              void* d_out, int out_size, void* d_ws, size_t ws_size,
                              hipStream_t stream) {
    const float* x   = (const float*)d_in[0];
    const float* ew1 = (const float*)d_in[1];
    const float* eb1 = (const float*)d_in[2];
    const float* ew2 = (const float*)d_in[3];
    const float* eb2 = (const float*)d_in[4];
    const float* cb  = (const float*)d_in[5];
    const float* dw1 = (const float*)d_in[6];
    const float* db1 = (const float*)d_in[7];
    const float* dw2 = (const float*)d_in[8];
    const float* db2 = (const float*)d_in[9];

    float* out = (float*)d_out;
    float* z   = out;
    float* zq  = out + (size_t)BATCH * ZDIM;
    float* rec = zq + (size_t)BATCH * EDIM;

    char* ws = (char*)d_ws;
    float* h    = (float*)(ws);                               // 8 MB
    float* h2   = (float*)(ws + 8388608);                     // 8 MB
    unsigned short* hb   = (unsigned short*)(ws + 16777216);  // 4 MB
    unsigned short* w2bt = (unsigned short*)(ws + 20971520);  // 16.75 MB
    int*   tok  = (int*)(ws + 37748736);
    float* s1v  = (float*)(ws + 38273024);
    int*   amb  = (int*)(ws + 38797312);
    int*   cnt  = (int*)(ws + 39321600);
    const size_t WS_NEED = 39321856;

    dim3 blk(256);
    const bool fast = ws_size >= WS_NEED;

    // encoder layer 1 (f32 exact — feeds the exact-recompute path)
    gemm_f32_64<true ><<<dim3(DMODEL / 64, BATCH / 64), blk, 0, stream>>>(
        x, ew1, eb1, h, BATCH, DMODEL, DMODEL);

    if (fast) {
        cvt_to_bf16<<<dim3(BATCH * DMODEL / 4 / 256), blk, 0, stream>>>(
            h, hb, BATCH * DMODEL);
        transpose_to_bf16<<<dim3(ZDIM / 32, DMODEL / 32), blk, 0, stream>>>(
            ew2, w2bt, DMODEL, ZDIM);
        gemm_mfma_bf16<<<dim3(ZDIM / 128, BATCH / 128), blk, 0, stream>>>(
            hb, w2bt, eb2, z, BATCH, ZDIM, DMODEL);
        zero_count<<<dim3(1), dim3(64), 0, stream>>>(cnt);
        sample_tokens_gap<<<dim3(BATCH * KTOK / 4), blk, 0, stream>>>(
            z, tok, s1v, amb, cnt);
        refine_tokens<<<dim3(2048), dim3(64), 0, stream>>>(
            z, h, ew2, eb2, amb, cnt, s1v, tok);
    } else {
        gemm_f32<false><<<dim3(ZDIM / 128, BATCH / 128), blk, 0, stream>>>(
            h, ew2, eb2, z, BATCH, ZDIM, DMODEL);
        sample_tokens_simple<<<dim3(BATCH * KTOK / 4), blk, 0, stream>>>(z, tok);
    }

    gather_zq<<<dim3(BATCH), blk, 0, stream>>>(tok, cb, zq);

    // decoder (f32 exact)
    gemm_f32_64<true ><<<dim3(DMODEL / 64, BATCH / 64), blk, 0, stream>>>(
        zq, dw1, db1, h2, BATCH, DMODEL, EDIM);
    gemm_f32_64<false><<<dim3(DMODEL / 64, BATCH / 64), blk, 0, stream>>>(
        h2, dw2, db2, rec, BATCH, DMODEL, DMODEL);
}

// Round 4
// 448.697 us; speedup vs baseline: 2.5624x; 1.2732x over previous
//
#include <hip/hip_runtime.h>
#include <hip/hip_bf16.h>
#include <math.h>
#include <stdint.h>

// ---------------------------------------------------------------------------
// VectorTokenizer: x ->(enc MLP)-> z -> categorical(threefry key(1)) tokens
//   -> z_q = sum of codebook rows -> (dec MLP) -> rec
// Outputs concatenated: z (4096*16384) | z_q (4096*256) | rec (4096*512), f32
//
// R4: refine rewritten — w2 transposed to f32 [N][K] (fused into the bf16
// transpose kernel) so exact recompute reads contiguous rows; candidates
// ballot-compacted, one lane per candidate. Old refine kept as ws fallback.
// ---------------------------------------------------------------------------

#define BATCH 4096
#define KTOK  32
#define VOCAB 512
#define DMODEL 512
#define ZDIM  16384
#define EDIM  256
#define MARGIN 0.03125f

typedef __attribute__((ext_vector_type(8))) short short8v;
typedef __attribute__((ext_vector_type(4))) float f32x4;

// ----------------------- threefry2x32 (JAX-compatible) ---------------------
__device__ __forceinline__ uint32_t rotl32(uint32_t v, int r) {
    return (v << r) | (v >> (32 - r));
}

__device__ __forceinline__ void threefry2x32(uint32_t k0, uint32_t k1,
                                             uint32_t x0, uint32_t x1,
                                             uint32_t& y0, uint32_t& y1) {
    uint32_t ks0 = k0, ks1 = k1, ks2 = k0 ^ k1 ^ 0x1BD11BDAu;
    x0 += ks0; x1 += ks1;
#define TFR(r) { x0 += x1; x1 = rotl32(x1, r); x1 ^= x0; }
    TFR(13) TFR(15) TFR(26) TFR(6)
    x0 += ks1; x1 += ks2 + 1u;
    TFR(17) TFR(29) TFR(16) TFR(24)
    x0 += ks2; x1 += ks0 + 2u;
    TFR(13) TFR(15) TFR(26) TFR(6)
    x0 += ks0; x1 += ks1 + 3u;
    TFR(17) TFR(29) TFR(16) TFR(24)
    x0 += ks1; x1 += ks2 + 4u;
    TFR(13) TFR(15) TFR(26) TFR(6)
    x0 += ks2; x1 += ks0 + 5u;
#undef TFR
    y0 = x0; y1 = x1;
}

// exact path (refine): matches JAX bit-for-bit
__device__ __forceinline__ float jax_gumbel(uint64_t e) {
    const float TINY = 1.17549435e-38f;
    uint32_t y0, y1;
    threefry2x32(0u, 1u, (uint32_t)(e >> 32), (uint32_t)(e & 0xffffffffull), y0, y1);
    uint32_t bits = y0 ^ y1;
    float u = __uint_as_float(0x3f800000u | (bits >> 9)) - 1.0f;
    u = u * 1.0f + TINY;
    u = fmaxf(TINY, u);
    return -logf(-logf(u));
}

// fast path (sampler filter): |g_fast - g_exact| <~ 1e-4 << MARGIN
__device__ __forceinline__ float fast_gumbel(uint32_t e32) {
    const float TINY = 1.17549435e-38f;
    const float LN2 = 0.69314718056f;
    uint32_t y0, y1;
    threefry2x32(0u, 1u, 0u, e32, y0, y1);
    uint32_t bits = y0 ^ y1;
    float f = __uint_as_float(0x3f800000u | (bits >> 9));  // [1,2)
    float u = f - 1.0f;          // exact (Sterbenz)
    float d = 2.0f - f;          // exact = 1-u
    u = fmaxf(u, TINY);
    float e_hw = -LN2 * __builtin_amdgcn_logf(u);
    float e_poly = d * fmaf(d, fmaf(d, 0.33333333f, 0.5f), 1.0f);
    float e = (d < 0.002f) ? e_poly : e_hw;
    return -LN2 * __builtin_amdgcn_logf(e);
}

__device__ __forceinline__ unsigned short f32_to_bf16_rne(float f) {
    uint32_t u = __float_as_uint(f);
    uint32_t r = (u + 0x7fffu + ((u >> 16) & 1u)) >> 16;
    return (unsigned short)r;
}

// ------------------ tiled f32 GEMM, 64x64 (small layers) -------------------
template<bool RELU>
__global__ __launch_bounds__(256)
void gemm_f32_64(const float* __restrict__ A, const float* __restrict__ B,
                 const float* __restrict__ bias, float* __restrict__ C,
                 int M, int N, int K) {
    constexpr int BK = 16;
    __shared__ __align__(16) float As[BK][68];
    __shared__ __align__(16) float Bs[BK][68];

    const int tid = threadIdx.x;
    const int tx = tid % 16;
    const int ty = tid / 16;
    const int brow = blockIdx.y * 64;
    const int bcol = blockIdx.x * 64;

    float acc[4][4] = {};

    for (int k0 = 0; k0 < K; k0 += BK) {
        {
            int r = tid >> 2, c4 = tid & 3;
            float4 v = *(const float4*)&A[(size_t)(brow + r) * K + k0 + c4 * 4];
            As[c4 * 4 + 0][r] = v.x;
            As[c4 * 4 + 1][r] = v.y;
            As[c4 * 4 + 2][r] = v.z;
            As[c4 * 4 + 3][r] = v.w;
        }
        {
            int r = tid >> 4, c4 = tid & 15;
            *(float4*)&Bs[r][c4 * 4] = *(const float4*)&B[(size_t)(k0 + r) * N + bcol + c4 * 4];
        }
        __syncthreads();

#pragma unroll
        for (int kk = 0; kk < BK; ++kk) {
            float a[4], b[4];
            *(float4*)&a[0] = *(const float4*)&As[kk][ty * 4];
            *(float4*)&b[0] = *(const float4*)&Bs[kk][tx * 4];
#pragma unroll
            for (int i = 0; i < 4; ++i)
#pragma unroll
                for (int j = 0; j < 4; ++j)
                    acc[i][j] = fmaf(a[i], b[j], acc[i][j]);
        }
        __syncthreads();
    }

#pragma unroll
    for (int i = 0; i < 4; ++i) {
        int row = brow + ty * 4 + i;
        int col = bcol + tx * 4;
        float4 v;
        v.x = acc[i][0] + bias[col + 0];
        v.y = acc[i][1] + bias[col + 1];
        v.z = acc[i][2] + bias[col + 2];
        v.w = acc[i][3] + bias[col + 3];
        if (RELU) {
            v.x = fmaxf(v.x, 0.0f); v.y = fmaxf(v.y, 0.0f);
            v.z = fmaxf(v.z, 0.0f); v.w = fmaxf(v.w, 0.0f);
        }
        *(float4*)&C[(size_t)row * N + col] = v;
    }
}

// ---------------- tiled f32 GEMM, 128x128 (fallback big) -------------------
template<bool RELU>
__global__ __launch_bounds__(256)
void gemm_f32(const float* __restrict__ A, const float* __restrict__ B,
              const float* __restrict__ bias, float* __restrict__ C,
              int M, int N, int K) {
    constexpr int BM = 128, BN = 128, BK = 16, TM = 8, TN = 8;
    __shared__ __align__(16) float As[BK][BM + 4];
    __shared__ __align__(16) float Bs[BK][BN + 4];

    const int tid = threadIdx.x;
    const int tx = tid % (BN / TN);
    const int ty = tid / (BN / TN);
    const int brow = blockIdx.y * BM;
    const int bcol = blockIdx.x * BN;

    float acc[TM][TN] = {};

    for (int k0 = 0; k0 < K; k0 += BK) {
#pragma unroll
        for (int f = tid; f < BM * BK / 4; f += 256) {
            int r = f / (BK / 4);
            int c4 = f % (BK / 4);
            float4 v = *(const float4*)&A[(size_t)(brow + r) * K + k0 + c4 * 4];
            As[c4 * 4 + 0][r] = v.x;
            As[c4 * 4 + 1][r] = v.y;
            As[c4 * 4 + 2][r] = v.z;
            As[c4 * 4 + 3][r] = v.w;
        }
#pragma unroll
        for (int f = tid; f < BK * BN / 4; f += 256) {
            int r = f / (BN / 4);
            int c4 = f % (BN / 4);
            *(float4*)&Bs[r][c4 * 4] = *(const float4*)&B[(size_t)(k0 + r) * N + bcol + c4 * 4];
        }
        __syncthreads();

#pragma unroll
        for (int kk = 0; kk < BK; ++kk) {
            float a[TM], b[TN];
            *(float4*)&a[0] = *(const float4*)&As[kk][ty * TM];
            *(float4*)&a[4] = *(const float4*)&As[kk][ty * TM + 4];
            *(float4*)&b[0] = *(const float4*)&Bs[kk][tx * TN];
            *(float4*)&b[4] = *(const float4*)&Bs[kk][tx * TN + 4];
#pragma unroll
            for (int i = 0; i < TM; ++i)
#pragma unroll
                for (int j = 0; j < TN; ++j)
                    acc[i][j] = fmaf(a[i], b[j], acc[i][j]);
        }
        __syncthreads();
    }

#pragma unroll
    for (int i = 0; i < TM; ++i) {
        int row = brow + ty * TM + i;
#pragma unroll
        for (int j = 0; j < TN; j += 4) {
            int col = bcol + tx * TN + j;
            float4 v;
            v.x = acc[i][j + 0] + bias[col + 0];
            v.y = acc[i][j + 1] + bias[col + 1];
            v.z = acc[i][j + 2] + bias[col + 2];
            v.w = acc[i][j + 3] + bias[col + 3];
            if (RELU) {
                v.x = fmaxf(v.x, 0.0f); v.y = fmaxf(v.y, 0.0f);
                v.z = fmaxf(v.z, 0.0f); v.w = fmaxf(v.w, 0.0f);
            }
            *(float4*)&C[(size_t)row * N + col] = v;
        }
    }
}

// --------------------- f32 -> bf16 elementwise convert ---------------------
__global__ __launch_bounds__(256)
void cvt_to_bf16(const float* __restrict__ src, unsigned short* __restrict__ dst,
                 int n) {
    int i = blockIdx.x * 256 + threadIdx.x;
    if (i * 4 < n) {
        float4 v = *(const float4*)&src[i * 4];
        ushort4 o;
        o.x = f32_to_bf16_rne(v.x);
        o.y = f32_to_bf16_rne(v.y);
        o.z = f32_to_bf16_rne(v.z);
        o.w = f32_to_bf16_rne(v.w);
        *(ushort4*)&dst[i * 4] = o;
    }
}

// ---- f32 [R][C] -> bf16 [C][R] transpose, optionally also f32 [C][R] ------
__global__ __launch_bounds__(256)
void transpose_w2(const float* __restrict__ src, unsigned short* __restrict__ dstb,
                  float* __restrict__ dstf, int R, int C, int writeF) {
    __shared__ float tile[32][33];
    const int c0 = blockIdx.x * 32, r0 = blockIdx.y * 32;
    const int tx = threadIdx.x % 32, ty = threadIdx.x / 32;
#pragma unroll
    for (int i = ty; i < 32; i += 8)
        tile[i][tx] = src[(size_t)(r0 + i) * C + c0 + tx];
    __syncthreads();
#pragma unroll
    for (int i = ty; i < 32; i += 8) {
        float v = tile[tx][i];
        size_t o = (size_t)(c0 + i) * R + r0 + tx;
        dstb[o] = f32_to_bf16_rne(v);
        if (writeF) dstf[o] = v;
    }
}

// ------------------------- bf16 MFMA GEMM ----------------------------------
__global__ __launch_bounds__(256)
void gemm_mfma_bf16(const unsigned short* __restrict__ A,
                    const unsigned short* __restrict__ Bt,
                    const float* __restrict__ bias,
                    float* __restrict__ C,
                    int M, int N, int K) {
    constexpr int BM = 128, BN = 128, BK = 32;
    __shared__ unsigned short As[BM * BK];
    __shared__ unsigned short Bs[BN * BK];

    const int nwg = gridDim.x * gridDim.y;
    const int lid = blockIdx.y * gridDim.x + blockIdx.x;
    const int cpx = nwg >> 3;
    const int swz = (lid & 7) * cpx + (lid >> 3);
    const int bx = swz % gridDim.x;
    const int by = swz / gridDim.x;

    const int tid = threadIdx.x;
    const int wid = tid >> 6;
    const int lane = tid & 63;
    const int wr = wid >> 1, wc = wid & 1;
    const int l15 = lane & 15, lq = lane >> 4;
    const int brow = by * BM;
    const int bcol = bx * BN;

    const int g1 = tid;
    const int g2 = tid + 256;
    const size_t a1 = (size_t)(brow + (g1 >> 2)) * K + (g1 & 3) * 8;
    const size_t a2 = (size_t)(brow + (g2 >> 2)) * K + (g2 & 3) * 8;
    const size_t b1 = (size_t)(bcol + (g1 >> 2)) * K + (g1 & 3) * 8;
    const size_t b2 = (size_t)(bcol + (g2 >> 2)) * K + (g2 & 3) * 8;
    unsigned short* as_base1 = As + (size_t)wid * 64 * 8;
    unsigned short* as_base2 = As + (size_t)(256 + wid * 64) * 8;
    unsigned short* bs_base1 = Bs + (size_t)wid * 64 * 8;
    unsigned short* bs_base2 = Bs + (size_t)(256 + wid * 64) * 8;

    f32x4 acc[4][4];
#pragma unroll
    for (int m = 0; m < 4; ++m)
#pragma unroll
        for (int n = 0; n < 4; ++n) acc[m][n] = (f32x4){0.f, 0.f, 0.f, 0.f};

    for (int k0 = 0; k0 < K; k0 += BK) {
        __builtin_amdgcn_global_load_lds(
            (const __attribute__((address_space(1))) unsigned int*)(A + a1 + k0),
            (__attribute__((address_space(3))) unsigned int*)as_base1, 16, 0, 0);
        __builtin_amdgcn_global_load_lds(
            (const __attribute__((address_space(1))) unsigned int*)(A + a2 + k0),
            (__attribute__((address_space(3))) unsigned int*)as_base2, 16, 0, 0);
        __builtin_amdgcn_global_load_lds(
            (const __attribute__((address_space(1))) unsigned int*)(Bt + b1 + k0),
            (__attribute__((address_space(3))) unsigned int*)bs_base1, 16, 0, 0);
        __builtin_amdgcn_global_load_lds(
            (const __attribute__((address_space(1))) unsigned int*)(Bt + b2 + k0),
            (__attribute__((address_space(3))) unsigned int*)bs_base2, 16, 0, 0);
        __syncthreads();

        short8v af[4], bf[4];
#pragma unroll
        for (int m = 0; m < 4; ++m)
            af[m] = *(const short8v*)&As[(wr * 64 + m * 16 + l15) * BK + lq * 8];
#pragma unroll
        for (int n = 0; n < 4; ++n)
            bf[n] = *(const short8v*)&Bs[(wc * 64 + n * 16 + l15) * BK + lq * 8];
#pragma unroll
        for (int m = 0; m < 4; ++m)
#pragma unroll
            for (int n = 0; n < 4; ++n)
                acc[m][n] = __builtin_amdgcn_mfma_f32_16x16x32_bf16(
                    af[m], bf[n], acc[m][n], 0, 0, 0);
        __syncthreads();
    }

#pragma unroll
    for (int m = 0; m < 4; ++m) {
#pragma unroll
        for (int n = 0; n < 4; ++n) {
            int col = bcol + wc * 64 + n * 16 + l15;
            float bv = bias[col];
#pragma unroll
            for (int r = 0; r < 4; ++r) {
                int row = brow + wr * 64 + m * 16 + lq * 4 + r;
                C[(size_t)row * N + col] = acc[m][n][r] + bv;
            }
        }
    }
}

// ----------- categorical sampling w/ top-2 gap (1 wave / token) ------------
__global__ __launch_bounds__(256)
void sample_tokens_gap(const float* __restrict__ z, int* __restrict__ tokens,
                       float* __restrict__ s1v, int* __restrict__ amb,
                       int* __restrict__ ambCount) {
    const int wave = threadIdx.x >> 6;
    const int lane = threadIdx.x & 63;
    const uint32_t t = blockIdx.x * 4 + wave;
    const float* zr = z + (size_t)t * VOCAB;

    float s1 = -INFINITY, s2 = -INFINITY;
    int v1 = 0;
#pragma unroll
    for (int half = 0; half < 2; ++half) {
        int e0 = half * 256 + lane * 4;
        float4 zv = *(const float4*)&zr[e0];
        float zs[4] = {zv.x, zv.y, zv.z, zv.w};
#pragma unroll
        for (int j = 0; j < 4; ++j) {
            int v = e0 + j;
            float s = zs[j] + fast_gumbel(t * (uint32_t)VOCAB + v);
            if (s > s1 || (s == s1 && v < v1)) { s2 = s1; s1 = s; v1 = v; }
            else if (s > s2) s2 = s;
        }
    }
#pragma unroll
    for (int off = 32; off > 0; off >>= 1) {
        float os1 = __shfl_down(s1, off);
        int ov1 = __shfl_down(v1, off);
        float os2 = __shfl_down(s2, off);
        if (os1 > s1 || (os1 == s1 && ov1 < v1)) {
            s2 = fmaxf(s1, os2); s1 = os1; v1 = ov1;
        } else {
            s2 = fmaxf(os1, s2);
        }
    }
    if (lane == 0) {
        tokens[t] = v1;
        s1v[t] = s1;
        if (s1 - s2 < MARGIN) {
            int idx = atomicAdd(ambCount, 1);
            amb[idx] = (int)t;
        }
    }
}

// ------ refine v2: w2t f32 rows, ballot-compacted candidates ---------------
// one wave (64 thr) per ambiguous token
__global__ __launch_bounds__(64)
void refine_tokens2(const float* __restrict__ z, const float* __restrict__ h,
                    const float* __restrict__ w2t, const float* __restrict__ eb2,
                    const int* __restrict__ amb, const int* __restrict__ ambCount,
                    const float* __restrict__ s1v, int* __restrict__ tok) {
    __shared__ float hrow[DMODEL];
    __shared__ int candv[64];
    const int cnt = *ambCount;
    const int lane = threadIdx.x;

    for (int i = blockIdx.x; i < cnt; i += gridDim.x) {
        const int t = amb[i];
        const int b = t >> 5;
        const int kb = t & 31;
        const float* zr = z + (size_t)t * VOCAB;
        const float s1 = s1v[t];

        // stage h row (512 f32) into LDS: 8 per lane
        {
            float4 hv0 = *(const float4*)&h[(size_t)b * DMODEL + lane * 8];
            float4 hv1 = *(const float4*)&h[(size_t)b * DMODEL + lane * 8 + 4];
            *(float4*)&hrow[lane * 8] = hv0;
            *(float4*)&hrow[lane * 8 + 4] = hv1;
        }

        // fast scores + ballot compaction of in-margin candidates
        int base = 0;
#pragma unroll
        for (int half = 0; half < 2; ++half) {
            int e0 = half * 256 + lane * 4;
            float4 zv = *(const float4*)&zr[e0];
            float zs[4] = {zv.x, zv.y, zv.z, zv.w};
#pragma unroll
            for (int j = 0; j < 4; ++j) {
                int v = e0 + j;
                float s = zs[j] + fast_gumbel((uint32_t)t * VOCAB + v);
                bool pred = (s >= s1 - MARGIN);
                unsigned long long mask = __ballot(pred);
                if (pred) {
                    int slot = base + __popcll(mask & ((1ull << lane) - 1ull));
                    if (slot < 64) candv[slot] = v;
                }
                base += __popcll(mask);
            }
        }
        __syncthreads();   // 1-wave block: LDS visibility
        const int ncand = base < 64 ? base : 64;

        // exact recompute: one lane per candidate, contiguous w2t row
        float bestE = -INFINITY;
        int bestV = VOCAB;
        if (lane < ncand) {
            const int v = candv[lane];
            const int n = kb * VOCAB + v;
            const float* wr_ = w2t + (size_t)n * DMODEL;
            float acc = 0.f;
#pragma unroll 8
            for (int k = 0; k < DMODEL; ++k)
                acc = fmaf(hrow[k], wr_[k], acc);
            bestE = acc + eb2[n] + jax_gumbel((uint64_t)t * VOCAB + v);
            bestV = v;
        }
#pragma unroll
        for (int off = 32; off > 0; off >>= 1) {
            float oe = __shfl_down(bestE, off);
            int ov = __shfl_down(bestV, off);
            if (oe > bestE || (oe == bestE && ov < bestV)) { bestE = oe; bestV = ov; }
        }
        if (lane == 0) tok[t] = bestV;
        __syncthreads();
    }
}

// --------- refine v1 (fallback when ws too small for w2t) ------------------
__global__ __launch_bounds__(64)
void refine_tokens(const float* __restrict__ z, const float* __restrict__ h,
                   const float* __restrict__ w2, const float* __restrict__ eb2,
                   const int* __restrict__ amb, const int* __restrict__ ambCount,
                   const float* __restrict__ s1v, int* __restrict__ tok) {
    const int cnt = *ambCount;
    const int lane = threadIdx.x;
    for (int i = blockIdx.x; i < cnt; i += gridDim.x) {
        const int t = amb[i];
        const int b = t >> 5;
        const int kb = t & 31;
        const float* zr = z + (size_t)t * VOCAB;
        const float s1 = s1v[t];
        float bestE = -INFINITY;
        int bestV = VOCAB;
#pragma unroll 1
        for (int r = 0; r < 8; ++r) {
            const int v = r * 64 + lane;
            const float g = jax_gumbel((uint64_t)t * VOCAB + v);
            const float sbf = zr[v] + g;
            float ex = -INFINITY;
            if (sbf >= s1 - MARGIN) {
                const float* hr = h + (size_t)b * DMODEL;
                const float* wcol = w2 + (size_t)(kb * VOCAB + v);
                float acc = 0.f;
#pragma unroll 8
                for (int k = 0; k < DMODEL; ++k)
                    acc = fmaf(hr[k], wcol[(size_t)k * ZDIM], acc);
                ex = acc + eb2[kb * VOCAB + v] + g;
            }
            if (ex > bestE || (ex == bestE && v < bestV)) { bestE = ex; bestV = v; }
        }
#pragma unroll
        for (int off = 32; off > 0; off >>= 1) {
            float oe = __shfl_down(bestE, off);
            int ov = __shfl_down(bestV, off);
            if (oe > bestE || (oe == bestE && ov < bestV)) { bestE = oe; bestV = ov; }
        }
        if (lane == 0) tok[t] = bestV;
    }
}

// ----------------- simple sampler (ws-too-small fallback) ------------------
__global__ __launch_bounds__(256)
void sample_tokens_simple(const float* __restrict__ z, int* __restrict__ tokens) {
    const int wave = threadIdx.x >> 6;
    const int lane = threadIdx.x & 63;
    const size_t t = (size_t)blockIdx.x * 4 + wave;
    const float* zr = z + t * VOCAB;
    float zv[8];
    *(float4*)&zv[0] = *(const float4*)&zr[lane * 8];
    *(float4*)&zv[4] = *(const float4*)&zr[lane * 8 + 4];
    const uint64_t ebase = t * (uint64_t)VOCAB + (uint64_t)lane * 8;
    float best = -INFINITY;
    int bestv = 0;
#pragma unroll
    for (int j = 0; j < 8; ++j) {
        float g = jax_gumbel(ebase + j);
        float s = zv[j] + g;
        int v = lane * 8 + j;
        if (s > best || (s == best && v < bestv)) { best = s; bestv = v; }
    }
#pragma unroll
    for (int off = 32; off > 0; off >>= 1) {
        float ob = __shfl_down(best, off);
        int ov = __shfl_down(bestv, off);
        if (ob > best || (ob == best && ov < bestv)) { best = ob; bestv = ov; }
    }
    if (lane == 0) tokens[t] = bestv;
}

__global__ __launch_bounds__(64)
void zero_count(int* p) { if (threadIdx.x == 0) *p = 0; }

// ------------------------- z_q gather (1 block / row) ----------------------
__global__ __launch_bounds__(256)
void gather_zq(const int* __restrict__ tokens, const float* __restrict__ codebook,
               float* __restrict__ zq) {
    const int b = blockIdx.x;
    const int d = threadIdx.x;
    float s = 0.0f;
#pragma unroll
    for (int k = 0; k < KTOK; ++k) {
        int tok = tokens[b * KTOK + k];
        s += codebook[(size_t)(k * VOCAB + tok) * EDIM + d];
    }
    zq[(size_t)b * EDIM + d] = s;
}

// ------------------------------- launcher ----------------------------------
extern "C" void kernel_launch(void* const* d_in, const int* in_sizes, int n_in,
                              void* d_out, int out_size, void* d_ws, size_t ws_size,
                              hipStream_t stream) {
    const float* x   = (const float*)d_in[0];
    const float* ew1 = (const float*)d_in[1];
    const float* eb1 = (const float*)d_in[2];
    const float* ew2 = (const float*)d_in[3];
    const float* eb2 = (const float*)d_in[4];
    const float* cb  = (const float*)d_in[5];
    const float* dw1 = (const float*)d_in[6];
    const float* db1 = (const float*)d_in[7];
    const float* dw2 = (const float*)d_in[8];
    const float* db2 = (const float*)d_in[9];

    float* out = (float*)d_out;
    float* z   = out;
    float* zq  = out + (size_t)BATCH * ZDIM;
    float* rec = zq + (size_t)BATCH * EDIM;

    char* ws = (char*)d_ws;
    float* h    = (float*)(ws);                               // 8 MB
    float* h2   = (float*)(ws + 8388608);                     // 8 MB
    unsigned short* hb   = (unsigned short*)(ws + 16777216);  // 4 MB
    unsigned short* w2bt = (unsigned short*)(ws + 20971520);  // 16 MB
    float* w2t  = (float*)(ws + 37748736);                    // 32 MB (fast2)
    // tail scratch: placed after w2t if fast2, else right after w2bt region
    const size_t WS_NEED1 = 39321856;                         // v1 layout end
    const size_t WS_NEED2 = 37748736 + 33554432 + 1572864 + 256;  // ~72.9 MB
    const bool fast  = ws_size >= WS_NEED1;
    const bool fast2 = ws_size >= WS_NEED2;
    char* tail = fast2 ? (ws + 37748736 + 33554432) : (ws + 37748736);
    int*   tok  = (int*)(tail);
    float* s1v  = (float*)(tail + 524288);
    int*   amb  = (int*)(tail + 1048576);
    int*   cnt  = (int*)(tail + 1572864);

    dim3 blk(256);

    // encoder layer 1 (f32 exact — feeds the exact-recompute path)
    gemm_f32_64<true ><<<dim3(DMODEL / 64, BATCH / 64), blk, 0, stream>>>(
        x, ew1, eb1, h, BATCH, DMODEL, DMODEL);

    if (fast) {
        cvt_to_bf16<<<dim3(BATCH * DMODEL / 4 / 256), blk, 0, stream>>>(
            h, hb, BATCH * DMODEL);
        transpose_w2<<<dim3(ZDIM / 32, DMODEL / 32), blk, 0, stream>>>(
            ew2, w2bt, w2t, DMODEL, ZDIM, fast2 ? 1 : 0);
        gemm_mfma_bf16<<<dim3(ZDIM / 128, BATCH / 128), blk, 0, stream>>>(
            hb, w2bt, eb2, z, BATCH, ZDIM, DMODEL);
        zero_count<<<dim3(1), dim3(64), 0, stream>>>(cnt);
        sample_tokens_gap<<<dim3(BATCH * KTOK / 4), blk, 0, stream>>>(
            z, tok, s1v, amb, cnt);
        if (fast2) {
            refine_tokens2<<<dim3(4096), dim3(64), 0, stream>>>(
                z, h, w2t, eb2, amb, cnt, s1v, tok);
        } else {
            refine_tokens<<<dim3(2048), dim3(64), 0, stream>>>(
                z, h, ew2, eb2, amb, cnt, s1v, tok);
        }
    } else {
        gemm_f32<false><<<dim3(ZDIM / 128, BATCH / 128), blk, 0, stream>>>(
            h, ew2, eb2, z, BATCH, ZDIM, DMODEL);
        sample_tokens_simple<<<dim3(BATCH * KTOK / 4), blk, 0, stream>>>(z, tok);
    }

    gather_zq<<<dim3(BATCH), blk, 0, stream>>>(tok, cb, zq);

    // decoder (f32 exact)
    gemm_f32_64<true ><<<dim3(DMODEL / 64, BATCH / 64), blk, 0, stream>>>(
        zq, dw1, db1, h2, BATCH, DMODEL, EDIM);
    gemm_f32_64<false><<<dim3(DMODEL / 64, BATCH / 64), blk, 0, stream>>>(
        h2, dw2, db2, rec, BATCH, DMODEL, DMODEL);
}